// Round 2
// baseline (83.957 us; speedup 1.0000x reference)
//
#include <hip/hip_runtime.h>

// Chamfer distance loss over equal-size clusters (C=128, P=1024, DIM=3).
// Reference excludes the highest cluster id -> clusters 0..126 contribute.
//
// R5 structure: occupancy x2. R3/R4 ran 254 blocks x 1024 thr = 1 block/CU
// = 4 waves/SIMD, and both the "more VALU per load batch" (R4) and LDS-
// traffic changes were neutral -> kernel is stall-bound, not LDS-bound.
// Split each (cluster, direction) into 4 query-quarter blocks:
//   grid = 127*2*4 = 1016 blocks, 512 threads, __launch_bounds__(512,8)
//   -> VGPR<=64, 32KB LDS/block -> 4 blocks/CU = 32 waves/CU = 8 waves/SIMD.
// Each block still sweeps ALL 1024 targets, so row-mins are complete within
// the block (no cross-block combine). Per-thread state trimmed to fit 64
// VGPRs: qn[] dropped; |a|^2 re-loaded from global in the epilogue (L2-hot)
// and added after the 16-way segment min (min distributes over +const).

#define PTS 1024
#define ACTIVE_CLUSTERS 127
#define QG   32             // queries per k-slice (= threads per segment)
#define Q    8              // queries per thread
#define SEG  16             // target segments (half-wave per segment)
#define TPB  512            // QG * SEG
#define TSEG (PTS / SEG)    // targets per segment = 64
#define QB   (Q * QG)       // queries per block = 256
#define NQB  (PTS / QB)     // query-quarter blocks per (cluster,dir) = 4

__global__ __launch_bounds__(TPB, 8) void chamfer_kernel(
    const float* __restrict__ pts_in,
    const float* __restrict__ pts_out,
    float* __restrict__ out)
{
    const int b   = blockIdx.x;
    const int c   = b >> 3;          // cluster
    const int dir = (b >> 2) & 1;    // direction
    const int qb  = b & 3;           // query quarter

    const float* __restrict__ query  = dir ? pts_out : pts_in;
    const float* __restrict__ target = dir ? pts_in  : pts_out;

    __shared__ __align__(16) float4 st[PTS];      // 16 KB: (x,y,z,|b|^2)
    __shared__ float pm[SEG * Q * QG];            // 16 KB: partial mins

    const int tid = threadIdx.x;
    const int qi  = tid & (QG - 1);
    const int seg = tid >> 5;
    const size_t base = (size_t)c * PTS * 3;

    // Stage all 1024 targets: two points per thread.
    for (int t = tid; t < PTS; t += TPB) {
        const float* tp = target + base + (size_t)t * 3;
        float x = tp[0], y = tp[1], z = tp[2];
        st[t] = make_float4(x, y, z, fmaf(x, x, fmaf(y, y, z * z)));
    }

    // Load this thread's Q query points (as -2*coords; |a|^2 re-loaded later).
    float qx[Q], qy[Q], qz[Q], mn[Q];
    #pragma unroll
    for (int k = 0; k < Q; ++k) {
        const float* qp = query + base + (size_t)(qb * QB + k * QG + qi) * 3;
        qx[k] = -2.0f * qp[0];
        qy[k] = -2.0f * qp[1];
        qz[k] = -2.0f * qp[2];
        mn[k] = 3.4e38f;
    }
    __syncthreads();

    // Sweep this segment's 64 targets, 2 at a time for v_min3 fusion.
    const int j0 = seg * TSEG;
    for (int jj = 0; jj < TSEG; jj += 2) {
        const float4 b0 = st[j0 + jj];
        const float4 b1 = st[j0 + jj + 1];
        #pragma unroll
        for (int k = 0; k < Q; ++k) {
            float s0 = fmaf(qx[k], b0.x, b0.w);
            s0 = fmaf(qy[k], b0.y, s0);
            s0 = fmaf(qz[k], b0.z, s0);
            float s1 = fmaf(qx[k], b1.x, b1.w);
            s1 = fmaf(qy[k], b1.y, s1);
            s1 = fmaf(qz[k], b1.z, s1);
            mn[k] = fminf(fminf(s0, s1), mn[k]);   // -> v_min3_f32
        }
    }

    // Store partial mins (raw; |a|^2 added after the segment-min combine).
    #pragma unroll
    for (int k = 0; k < Q; ++k)
        pm[(seg * Q + k) * QG + qi] = mn[k];
    __syncthreads();

    // Combine: thread tid < 256 owns local query q = tid.
    float v = 0.0f;
    if (tid < QB) {
        const int k2  = tid >> 5;
        const int qi2 = tid & (QG - 1);
        float m = 3.4e38f;
        #pragma unroll
        for (int s = 0; s < SEG; ++s)
            m = fminf(m, pm[(s * Q + k2) * QG + qi2]);
        // |a|^2 for this query (L2-hot reload; min distributes over +const).
        const float* qp = query + base + (size_t)(qb * QB + tid) * 3;
        float ax = qp[0], ay = qp[1], az = qp[2];
        v = m + fmaf(ax, ax, fmaf(ay, ay, az * az));
    }

    // Block sum: wave shuffle, cross-wave via LDS, one atomicAdd.
    #pragma unroll
    for (int off = 32; off > 0; off >>= 1)
        v += __shfl_down(v, off, 64);

    __shared__ float wsum[8];
    const int wave = tid >> 6;
    const int lane = tid & 63;
    if (lane == 0) wsum[wave] = v;
    __syncthreads();

    if (wave == 0) {
        float t = (lane < 8) ? wsum[lane] : 0.0f;
        #pragma unroll
        for (int off = 4; off > 0; off >>= 1)
            t += __shfl_down(t, off, 64);
        if (lane == 0) atomicAdd(out, t);
    }
}

extern "C" void kernel_launch(void* const* d_in, const int* in_sizes, int n_in,
                              void* d_out, int out_size, void* d_ws, size_t ws_size,
                              hipStream_t stream) {
    const float* input_points  = (const float*)d_in[0];
    const float* output_points = (const float*)d_in[2];
    float* out = (float*)d_out;

    hipMemsetAsync(out, 0, sizeof(float), stream);

    chamfer_kernel<<<dim3(ACTIVE_CLUSTERS * 2 * NQB), dim3(TPB), 0, stream>>>(
        input_points, output_points, out);
}